// Round 7
// baseline (457.837 us; speedup 1.0000x reference)
//
#include <hip/hip_runtime.h>

// MPLayer: out[i,m] = (1/K) sum_{j,l,n} edges[i,j,n] * nodes[nlist[i,j],l] * w[l,m,n]
// N=50000, K=32, F=128, E=16. Two-phase MFMA (fp16 in, fp32 acc).
// v7: no register-array pipelines (v3/v5/v6 all spilled/were defeated).
//   - gather: 1 dwordx4/lane -> conflict-free stride-33 LDS staging [c][j]
//     -> 8x b32 read + 4x v_perm = A-frag (v4-verified perm path).
//   - RPB=32 (halves w2t L2 restream), 8 waves, 8 chunks x 16 cols.
//   - double-buffered s_T, ONE barrier/chunk: phase1(ch+1) of all waves
//     overlaps phase2(ch); only scalar G/Gn values live across it.
//   - phase 2: wave = (itile, mpair): 1 t-frag + 2 w2t-frags per kt.

typedef _Float16 half8  __attribute__((ext_vector_type(8)));
typedef _Float16 half4v __attribute__((ext_vector_type(4)));
typedef float    float4v __attribute__((ext_vector_type(4)));
typedef int      int4v  __attribute__((ext_vector_type(4)));
typedef unsigned int uint;

#define NF 128
#define NK 32
#define NE 16
#define RPB 32

// ---- fused prep: blocks [0,1024) build W2t, rest convert nodes to fp16 ----
// W2t order: o = m*2048 + C, C = ch*256 + n*16 + ll  <->  w[l=ch*16+ll][m][n]
// (matches phase-1 T store c' = c16*16 + quad*4 + g, i.e. c' = n*16 + l_local)
__global__ __launch_bounds__(256) void k_prep(const float* __restrict__ nodes,
                                              const float* __restrict__ w,
                                              _Float16* __restrict__ nodes_h,
                                              _Float16* __restrict__ w2t, int n4) {
    const int b = blockIdx.x;
    if (b < 1024) {
        int o  = b * 256 + threadIdx.x;      // 262144 exact
        int m  = o >> 11;
        int C  = o & 2047;
        int ch = C >> 8;
        int n  = (C >> 4) & 15;
        int ll = C & 15;
        int l  = ch * 16 + ll;
        w2t[o] = (_Float16)w[(l * NF + m) * NE + n];
    } else {
        int i = (b - 1024) * 256 + threadIdx.x;
        if (i < n4) {
            float4v v = ((const float4v*)nodes)[i];
            half4v h;
            h[0] = (_Float16)v[0]; h[1] = (_Float16)v[1];
            h[2] = (_Float16)v[2]; h[3] = (_Float16)v[3];
            ((half4v*)nodes_h)[i] = h;
        }
    }
}

// MFMA 16x16x32 f16 layouts (verified v1-v6):
//   A: lane holds A[m = lane&15][k = (lane>>4)*8 + jj]
//   B: lane holds B[k = (lane>>4)*8 + jj][n = lane&15]
//   C/D: lane holds D[row = (lane>>4)*4 + g][col = lane&15]
__global__ __launch_bounds__(512, 6) void k_mp(const _Float16* __restrict__ nodes_h,
                                               const int* __restrict__ nlist,
                                               const float* __restrict__ edges,
                                               const _Float16* __restrict__ w2t,
                                               float* __restrict__ out, int N) {
    // s_T: double-buffered, 32 i-rows x 256 halves/chunk, XOR-swizzled (32KB).
    // s_G: per-wave staging, 8 dword-cols x stride 33 (+pad) = conflict-free:
    //   write banks (c+j)%32, read banks (c+8q+t)%32 -- both collision-free.
    __shared__ __align__(16) _Float16 s_T[2][RPB * 256];
    __shared__ __align__(16) uint s_G[8][268];

    const int tid  = threadIdx.x;
    const int wv   = tid >> 6;
    const int ln   = tid & 63;
    const int quad = ln >> 4;
    const int c16  = ln & 15;
    const int row0 = blockIdx.x * RPB;
    const float4v zf = {0.f, 0.f, 0.f, 0.f};

    // ---- edge B-fragments + per-lane neighbor byte offsets (4 i-rows/wave) ----
    half8 fe[4];
    int nbj[4];
    #pragma unroll
    for (int r = 0; r < 4; ++r) {
        int rg = row0 + wv * 4 + r; if (rg > N - 1) rg = N - 1;
        const float* ep = edges + (size_t)rg * (NK * NE) + quad * (8 * NE) + c16;
        #pragma unroll
        for (int jj = 0; jj < 8; ++jj) fe[r][jj] = (_Float16)ep[jj * NE];
        nbj[r] = nlist[rg * NK + (ln & 31)] << 8;   // 256B per fp16 node row
    }

    const int hf = ln >> 5;                          // which 16B half of 32B chunk-row
    const char* gb = (const char*)nodes_h + hf * 16;
    uint* __restrict__ gst = &s_G[wv][0];
    const int wbase = (hf * 4) * 33 + (ln & 31);
    const int rbase = (c16 >> 1) * 33 + quad * 8;
    const uint psel = 0x05040100u + (uint)(c16 & 1) * 0x02020202u;

    // phase-2 role: itile = wv>>2 (i 0-15 or 16-31), m-pair = wv&3 (32 m-cols)
    const int it = wv >> 2, mp = wv & 3;
    const _Float16* wr0 = w2t + ((size_t)(mp * 32 + c16)) * 2048;
    const _Float16* wr1 = wr0 + (size_t)16 * 2048;
    float4v a0 = zf, a1 = zf;

    uint4 G = *(const uint4*)(gb + nbj[0]);          // prologue gather (ch0,r0)

    for (int ch = 0; ch < 8; ++ch) {
        // ===== phase 1: 4 i-rows, chunk = l-cols [ch*16, ch*16+16) =====
        #pragma unroll
        for (int r = 0; r < 4; ++r) {
            uint4 Gn = G;
            if (ch * 4 + r < 31) {                   // prefetch next gather
                const int r1 = (r + 1) & 3, ch1 = ch + ((r + 1) >> 2);
                Gn = *(const uint4*)(gb + nbj[r1] + ch1 * 32);
            }
            // stage G: dword-col c = hf*4+cc holds l-pair, row j (conflict-free)
            gst[wbase]      = G.x;
            gst[wbase + 33] = G.y;
            gst[wbase + 66] = G.z;
            gst[wbase + 99] = G.w;
            // transpose read: 8 j's of dword-col c16>>1 (pairs broadcast)
            uint d0 = gst[rbase + 0], d1 = gst[rbase + 1];
            uint d2 = gst[rbase + 2], d3 = gst[rbase + 3];
            uint d4 = gst[rbase + 4], d5 = gst[rbase + 5];
            uint d6 = gst[rbase + 6], d7 = gst[rbase + 7];
            int4v pv;
            pv[0] = (int)__builtin_amdgcn_perm(d1, d0, psel);
            pv[1] = (int)__builtin_amdgcn_perm(d3, d2, psel);
            pv[2] = (int)__builtin_amdgcn_perm(d5, d4, psel);
            pv[3] = (int)__builtin_amdgcn_perm(d7, d6, psel);
            half8 av = __builtin_bit_cast(half8, pv);
            float4v d = __builtin_amdgcn_mfma_f32_16x16x32_f16(av, fe[r], zf, 0, 0, 0);
            // store D: c' = c16*16 + quad*4 + g, phys = c' ^ ((il&7)<<3)
            const int il   = wv * 4 + r;
            const int cpr  = (c16 << 4) + (quad << 2);
            const int phys = cpr ^ ((il & 7) << 3);
            half4v hv;
            hv[0] = (_Float16)d[0]; hv[1] = (_Float16)d[1];
            hv[2] = (_Float16)d[2]; hv[3] = (_Float16)d[3];
            *(half4v*)&s_T[ch & 1][il * 256 + phys] = hv;
            G = Gn;
        }
        __syncthreads();   // publish chunk ch (single barrier; s_T double-buffered)

        // ===== phase 2: out_tile(it, mp) += T_chunk @ W2t_chunk^T =====
        const _Float16* w0 = wr0 + ch * 256;
        const _Float16* w1 = wr1 + ch * 256;
        const int ilr = it * 16 + c16;
        const int rsw = (ilr & 7) << 3;
        #pragma unroll
        for (int kt = 0; kt < 8; ++kt) {
            const int cb = (kt << 5) + (quad << 3);
            half8 t0 = *(const half8*)&s_T[ch & 1][ilr * 256 + (cb ^ rsw)];
            half8 b0 = *(const half8*)(w0 + cb);
            half8 b1 = *(const half8*)(w1 + cb);
            a0 = __builtin_amdgcn_mfma_f32_16x16x32_f16(t0, b0, a0, 0, 0, 0);
            a1 = __builtin_amdgcn_mfma_f32_16x16x32_f16(t0, b1, a1, 0, 0, 0);
        }
        // next phase1 writes buf[(ch+1)&1]; phase2 readers of buf[ch&1] are all
        // pre-barrier(ch+1) within each wave -> no WAR, one barrier per chunk.
    }

    // ---- epilogue: D[row = quad*4+g][col = c16], scale by 1/K ----
    const float sc = 1.0f / (float)NK;
    const int mb = mp * 32 + c16;
    #pragma unroll
    for (int g = 0; g < 4; ++g) {
        const int i0 = row0 + it * 16 + (quad << 2) + g;
        if (i0 < N) {
            out[(size_t)i0 * NF + mb]      = a0[g] * sc;
            out[(size_t)i0 * NF + mb + 16] = a1[g] * sc;
        }
    }
}

extern "C" void kernel_launch(void* const* d_in, const int* in_sizes, int n_in,
                              void* d_out, int out_size, void* d_ws, size_t ws_size,
                              hipStream_t stream) {
    const float* nodes = (const float*)d_in[0];
    const int*   nlist = (const int*)d_in[1];
    const float* edges = (const float*)d_in[2];
    const float* w     = (const float*)d_in[3];
    float* out = (float*)d_out;

    const int N = in_sizes[0] / NF;   // 50000

    _Float16* w2t     = (_Float16*)d_ws;                       // 512KB
    _Float16* nodes_h = (_Float16*)((char*)d_ws + 524288);     // 12.8MB

    const int n4 = (N * NF) / 4;                               // 1.6M float4s
    const int prep_blocks = 1024 + (n4 + 255) / 256;
    k_prep<<<prep_blocks, 256, 0, stream>>>(nodes, w, nodes_h, w2t, n4);

    const int blocks = (N + RPB - 1) / RPB;                    // 1563
    k_mp<<<blocks, 512, 0, stream>>>(nodes_h, nlist, edges, w2t, out, N);
}